// Round 1
// baseline (775.909 us; speedup 1.0000x reference)
//
#include <hip/hip_runtime.h>

#define B_TOTAL 16384
#define INPUT   512
#define HID     128
#define OUTW    64
#define STEPS   10
#define GATES   512   // 4*HID

// ws layout (floats):
//   W_effT [512 k-rows? no: [128][512]]  off 0       (W_hh + W_ih@W_out, transposed: [k][j])
//   W_hhT  [128][512]                    off 65536
//   W_initT[512][128]                    off 131072
//   W_outT [128][64]                     off 196608
//   b_all  [512]                         off 204800  (b_ih+b_hh+W_ih@b_out)
//   b2     [512]                         off 205312  (b_ih+b_hh, for t=0 where o=0)
// total 205824 floats = 823 KB

__global__ __launch_bounds__(128) void precompute_kernel(
    const float* __restrict__ W_ih, const float* __restrict__ W_hh,
    const float* __restrict__ b_ih, const float* __restrict__ b_hh,
    const float* __restrict__ W_init, const float* __restrict__ W_out,
    const float* __restrict__ b_out, float* __restrict__ ws)
{
    const int j = blockIdx.x;   // gate row 0..511 (also reused as input-col for W_initT)
    const int k = threadIdx.x;  // 0..127
    float* W_effT  = ws;
    float* W_hhT   = ws + 65536;
    float* W_initT = ws + 131072;
    float* W_outT  = ws + 196608;
    float* b_all   = ws + 204800;
    float* b2      = ws + 205312;

    float whh = W_hh[j*HID + k];
    float acc = whh;
    for (int m = 0; m < OUTW; ++m)
        acc += W_ih[j*OUTW + m] * W_out[m*HID + k];
    W_effT[k*GATES + j] = acc;       // [k][j]
    W_hhT [k*GATES + j] = whh;       // [k][j]
    W_initT[j*HID + k] = W_init[k*INPUT + j];   // j=input col, k=h
    if (j < OUTW) W_outT[k*OUTW + j] = W_out[j*HID + k];
    if (k == 0) {
        float s = 0.f;
        for (int m = 0; m < OUTW; ++m) s += W_ih[j*OUTW + m] * b_out[m];
        float bb = b_ih[j] + b_hh[j];
        b_all[j] = bb + s;
        b2[j]    = bb;
    }
}

__device__ __forceinline__ float fast_sigmoid(float x) {
    return 1.f / (1.f + __builtin_amdgcn_exp2f(-1.4426950408889634f * x));
}
__device__ __forceinline__ float fast_tanh(float x) {
    // tanh(x) = 1 - 2/(1+e^{2x}); saturates correctly for |x| large
    return 1.f - 2.f / (1.f + __builtin_amdgcn_exp2f(2.8853900817779268f * x));
}

#define RPB 32    // rows per block
#define TPB 512

__global__ __launch_bounds__(TPB, 4) void lstm_kernel(
    const float* __restrict__ x, const float* __restrict__ ws,
    const float* __restrict__ b_init, const float* __restrict__ b_out,
    float* __restrict__ out)
{
    __shared__ float xs[RPB][INPUT];   // 64 KB (init phase only)
    __shared__ float hxs[RPB][HID];    // 16 KB

    const float* W_effT  = ws;
    const float* W_hhT   = ws + 65536;
    const float* W_initT = ws + 131072;
    const float* W_outT  = ws + 196608;
    const float* b_all   = ws + 204800;
    const float* b2      = ws + 205312;

    const int tid = threadIdx.x;
    const int h   = tid & 127;     // owned hidden index
    const int rq  = tid >> 7;      // 0..3 -> row block of 8
    const int b0  = blockIdx.x * RPB;

    // ---- stage x tile into LDS (coalesced float4) ----
    {
        const float4* xg  = (const float4*)(x + (size_t)b0 * INPUT);
        float4*       xsv = (float4*)&xs[0][0];
        #pragma unroll
        for (int i = 0; i < (RPB*INPUT/4)/TPB; ++i)   // 8
            xsv[tid + i*TPB] = xg[tid + i*TPB];
    }
    __syncthreads();

    // ---- init GEMM: hx0[r][h] = b_init[h] + sum_k x[r][k]*W_init[h][k] ----
    float cx[8];
    {
        float acc[8];
        const float binit = b_init[h];
        #pragma unroll
        for (int r = 0; r < 8; ++r) acc[r] = binit;
        for (int k0 = 0; k0 < INPUT; k0 += 4) {
            float w0 = W_initT[(k0+0)*HID + h];
            float w1 = W_initT[(k0+1)*HID + h];
            float w2 = W_initT[(k0+2)*HID + h];
            float w3 = W_initT[(k0+3)*HID + h];
            #pragma unroll
            for (int r = 0; r < 8; ++r) {
                float4 xv = *(const float4*)&xs[rq*8 + r][k0];
                acc[r] = fmaf(xv.x, w0, acc[r]);
                acc[r] = fmaf(xv.y, w1, acc[r]);
                acc[r] = fmaf(xv.z, w2, acc[r]);
                acc[r] = fmaf(xv.w, w3, acc[r]);
            }
        }
        #pragma unroll
        for (int r = 0; r < 8; ++r) { cx[r] = acc[r]; hxs[rq*8 + r][h] = acc[r]; }
    }
    __syncthreads();

    const int jo = tid & 63;   // out-GEMM column
    const int ro = tid >> 6;   // 0..7 -> rows {ro, 8+ro, 16+ro, 24+ro}
    const float boutj = b_out[jo];

    for (int t = 0; t < STEPS; ++t) {
        const float* Wt = (t == 0) ? W_hhT : W_effT;   // t=0: o==0, no folded term
        const float* bb = (t == 0) ? b2   : b_all;

        float aI[8], aF[8], aG[8], aO[8];
        {
            const float bIv = bb[h], bFv = bb[128+h], bGv = bb[256+h], bOv = bb[384+h];
            #pragma unroll
            for (int r = 0; r < 8; ++r) { aI[r]=bIv; aF[r]=bFv; aG[r]=bGv; aO[r]=bOv; }
        }
        for (int k0 = 0; k0 < HID; k0 += 4) {
            float wI[4], wF[4], wG[4], wO[4];
            #pragma unroll
            for (int i = 0; i < 4; ++i) {
                const float* wr = Wt + (size_t)(k0+i)*GATES;
                wI[i] = wr[      h];
                wF[i] = wr[128 + h];
                wG[i] = wr[256 + h];
                wO[i] = wr[384 + h];
            }
            #pragma unroll
            for (int r = 0; r < 8; ++r) {
                float4 hv = *(const float4*)&hxs[rq*8 + r][k0];
                aI[r] = fmaf(hv.x, wI[0], aI[r]); aI[r] = fmaf(hv.y, wI[1], aI[r]);
                aI[r] = fmaf(hv.z, wI[2], aI[r]); aI[r] = fmaf(hv.w, wI[3], aI[r]);
                aF[r] = fmaf(hv.x, wF[0], aF[r]); aF[r] = fmaf(hv.y, wF[1], aF[r]);
                aF[r] = fmaf(hv.z, wF[2], aF[r]); aF[r] = fmaf(hv.w, wF[3], aF[r]);
                aG[r] = fmaf(hv.x, wG[0], aG[r]); aG[r] = fmaf(hv.y, wG[1], aG[r]);
                aG[r] = fmaf(hv.z, wG[2], aG[r]); aG[r] = fmaf(hv.w, wG[3], aG[r]);
                aO[r] = fmaf(hv.x, wO[0], aO[r]); aO[r] = fmaf(hv.y, wO[1], aO[r]);
                aO[r] = fmaf(hv.z, wO[2], aO[r]); aO[r] = fmaf(hv.w, wO[3], aO[r]);
            }
        }
        __syncthreads();   // all reads of old hxs complete

        #pragma unroll
        for (int r = 0; r < 8; ++r) {
            float ig = fast_sigmoid(aI[r]);
            float fg = fast_sigmoid(aF[r]);
            float gg = fast_tanh(aG[r]);
            float og = fast_sigmoid(aO[r]);
            float c  = fmaf(fg, cx[r], ig * gg);
            cx[r] = c;
            hxs[rq*8 + r][h] = og * fast_tanh(c);
        }
        __syncthreads();   // new hxs visible

        // ---- out GEMM: o_t[row][jo] = b_out[jo] + sum_k hx[row][k]*W_out[jo][k] ----
        float oacc[4];
        #pragma unroll
        for (int rr = 0; rr < 4; ++rr) oacc[rr] = boutj;
        for (int k0 = 0; k0 < HID; k0 += 4) {
            float w0 = W_outT[(k0+0)*OUTW + jo];
            float w1 = W_outT[(k0+1)*OUTW + jo];
            float w2 = W_outT[(k0+2)*OUTW + jo];
            float w3 = W_outT[(k0+3)*OUTW + jo];
            #pragma unroll
            for (int rr = 0; rr < 4; ++rr) {
                float4 hv = *(const float4*)&hxs[rr*8 + ro][k0];
                oacc[rr] = fmaf(hv.x, w0, oacc[rr]);
                oacc[rr] = fmaf(hv.y, w1, oacc[rr]);
                oacc[rr] = fmaf(hv.z, w2, oacc[rr]);
                oacc[rr] = fmaf(hv.w, w3, oacc[rr]);
            }
        }
        #pragma unroll
        for (int rr = 0; rr < 4; ++rr) {
            int row = rr*8 + ro;
            out[(size_t)(b0 + row)*(STEPS*OUTW) + t*OUTW + jo] = oacc[rr];
        }
        // no barrier needed: next iteration only READS hxs until its own post-gates barrier
    }
}

extern "C" void kernel_launch(void* const* d_in, const int* in_sizes, int n_in,
                              void* d_out, int out_size, void* d_ws, size_t ws_size,
                              hipStream_t stream)
{
    const float* x      = (const float*)d_in[0];
    const float* W_ih   = (const float*)d_in[1];
    const float* W_hh   = (const float*)d_in[2];
    const float* b_ih   = (const float*)d_in[3];
    const float* b_hh   = (const float*)d_in[4];
    const float* W_init = (const float*)d_in[5];
    const float* b_init = (const float*)d_in[6];
    const float* W_out  = (const float*)d_in[7];
    const float* b_out  = (const float*)d_in[8];
    float* out = (float*)d_out;
    float* ws  = (float*)d_ws;

    precompute_kernel<<<GATES, HID, 0, stream>>>(W_ih, W_hh, b_ih, b_hh, W_init, W_out, b_out, ws);
    lstm_kernel<<<B_TOTAL/RPB, TPB, 0, stream>>>(x, ws, b_init, b_out, out);
}